// Round 1
// baseline (251.773 us; speedup 1.0000x reference)
//
#include <hip/hip_runtime.h>

#define TT 512
#define BB 256
#define DIN 128
#define DH 128

// ---------------------------------------------------------------------------
// Math simplification (exact, from the reference):
//   cx[b,:] and hx[b,:] are constant across the hidden dim (gates are [B,1]
//   scalars broadcast over D_H and cx starts at 0). So per (t,b) the state is
//   two scalars (h, c):
//     z_j  = zx[t,b,j] + h * swh_j + b_j           (j = 28 gate/qubit combos)
//     p_g  = prod_{q=1..7} cos(z_{g,q})
//     f,i,o = sigmoid(p); u = tanh(p)
//     c = f*c + i*u ;  h = o*tanh(c)
//   outs[t,b,:] = h (broadcast over 128), final hx = h, final cx = c.
//   qwf/qwi/qwu/qwo are analytically dead (diagonal RZ drops out of <Z0>).
// ---------------------------------------------------------------------------

// ws layout (floats):
//   zxb  [TT*BB*32]  : x-projection + bias, slot j' = gate*8 + (q-1); slot 7 = 0
//   h_buf[TT*BB]     : h(t,b)
//   c_buf[BB]        : final c(b)
//   swh  [32]        : row-sums of the hx-half of W rows (slot layout as zxb)

// ---- prep: swh[g*8+qi] = sum_d W_g[(qi+1)*256 + 128 + d] --------------------
__global__ __launch_bounds__(256) void qlstm_prep(
    const float* __restrict__ Wf, const float* __restrict__ Wi,
    const float* __restrict__ Wu, const float* __restrict__ Wo,
    float* __restrict__ swh)
{
    int tid  = threadIdx.x;      // 256 threads, 1 block
    int slot = tid >> 3;         // 0..31
    int s    = tid & 7;
    int g    = slot >> 3;        // 0..3
    int qi   = slot & 7;
    const float* W = (g == 0) ? Wf : ((g == 1) ? Wi : ((g == 2) ? Wu : Wo));
    float p = 0.f;
    if (qi < 7) {
        const float* row = W + (qi + 1) * 256 + 128 + s * 16;
#pragma unroll
        for (int k = 0; k < 16; ++k) p += row[k];
    }
    // reduce over the 8 lanes of this slot (groups of 8 stay inside a wave)
    p += __shfl_xor(p, 1);
    p += __shfl_xor(p, 2);
    p += __shfl_xor(p, 4);
    if (s == 0) swh[slot] = p;   // qi==7 -> 0 (neutral)
}

// ---- zx: zxb[row][slot] = x(row) . Wx_row + bias ---------------------------
__global__ __launch_bounds__(256) void qlstm_zx(
    const float* __restrict__ X,   // [TT*BB][128]
    const float* __restrict__ Wf, const float* __restrict__ bf,
    const float* __restrict__ Wi, const float* __restrict__ bi,
    const float* __restrict__ Wu, const float* __restrict__ bu,
    const float* __restrict__ Wo, const float* __restrict__ bo,
    float* __restrict__ zxb)       // [TT*BB][32]
{
    __shared__ float Wl[28][132];  // pad 132: float4 rows stay 16B aligned
    int tid = threadIdx.x;
    for (int idx = tid; idx < 28 * 128; idx += 256) {
        int jj = idx >> 7;         // 0..27
        int d  = idx & 127;
        int g  = jj / 7;
        int qi = jj - g * 7;
        const float* W = (g == 0) ? Wf : ((g == 1) ? Wi : ((g == 2) ? Wu : Wo));
        Wl[jj][d] = W[(qi + 1) * 256 + d];
    }
    __syncthreads();

    int rr = tid >> 5;             // 0..7 -> rows rr and rr+8 of this block
    int j  = tid & 31;             // 0..31 (28 compute, 4 write the zero slot)
    long rowbase = (long)blockIdx.x * 16;
    const float4* x0 = (const float4*)(X + (rowbase + rr) * 128);
    const float4* x1 = (const float4*)(X + (rowbase + rr + 8) * 128);
    if (j < 28) {
        int g  = j / 7;
        int qi = j - g * 7;
        const float* bp = (g == 0) ? bf : ((g == 1) ? bi : ((g == 2) ? bu : bo));
        float bias = bp[qi + 1];
        const float4* w4 = (const float4*)(&Wl[j][0]);
        float a0 = 0.f, a1 = 0.f;
#pragma unroll 8
        for (int k = 0; k < 32; ++k) {
            float4 w  = w4[k];
            float4 p0 = x0[k];
            float4 p1 = x1[k];
            a0 = fmaf(w.x, p0.x, a0); a0 = fmaf(w.y, p0.y, a0);
            a0 = fmaf(w.z, p0.z, a0); a0 = fmaf(w.w, p0.w, a0);
            a1 = fmaf(w.x, p1.x, a1); a1 = fmaf(w.y, p1.y, a1);
            a1 = fmaf(w.z, p1.z, a1); a1 = fmaf(w.w, p1.w, a1);
        }
        int slot = g * 8 + qi;
        zxb[(rowbase + rr) * 32 + slot]     = a0 + bias;
        zxb[(rowbase + rr + 8) * 32 + slot] = a1 + bias;
    } else {
        int g = j - 28;
        zxb[(rowbase + rr) * 32 + g * 8 + 7]     = 0.f;
        zxb[(rowbase + rr + 8) * 32 + g * 8 + 7] = 0.f;
    }
}

// ---- sequential core: 4 lanes per batch chain, DPP quad broadcasts ---------
template <int K>
__device__ __forceinline__ float quad_bcast(float v) {
    // quad_perm broadcast of quad-lane K: ctrl = K|K<<2|K<<4|K<<6 = K*0x55
    return __int_as_float(__builtin_amdgcn_mov_dpp(
        __float_as_int(v), K * 0x55, 0xf, 0xf, true));
}

__global__ __launch_bounds__(64) void qlstm_seq(
    const float* __restrict__ zxb,  // [TT*BB][32]
    const float* __restrict__ swh,  // [32]
    float* __restrict__ h_buf,      // [TT][BB]
    float* __restrict__ c_buf)      // [BB]
{
    int lane = threadIdx.x;                    // 64 = one wave
    int b    = blockIdx.x * 16 + (lane >> 2);  // batch chain
    int g    = lane & 3;                       // 0=f 1=i 2=u 3=o
    float4 s0 = *(const float4*)(swh + g * 8);
    float4 s1 = *(const float4*)(swh + g * 8 + 4);   // s1.w unused (slot 7)
    const float* p = zxb + b * 32 + g * 8;
    float4 cur0 = *(const float4*)p;
    float4 cur1 = *(const float4*)(p + 4);
    float h = 0.f, c = 0.f;
    const float a    = (g == 2) ? 2.f : -1.f;   // exp arg scale: tanh vs sigmoid
    const bool  lead = (g == 0);
    const bool  isU  = (g == 2);
    float* hp = h_buf + b;
#pragma unroll 1
    for (int t = 0; t < TT; ++t) {
        p += BB * 32;
        // prefetch next step (at t=TT-1 this overreads into h_buf: values
        // are discarded, region is inside ws -> safe)
        float4 n0 = *(const float4*)p;
        float4 n1 = *(const float4*)(p + 4);
        float z0 = fmaf(h, s0.x, cur0.x);
        float z1 = fmaf(h, s0.y, cur0.y);
        float z2 = fmaf(h, s0.z, cur0.z);
        float z3 = fmaf(h, s0.w, cur0.w);
        float z4 = fmaf(h, s1.x, cur1.x);
        float z5 = fmaf(h, s1.y, cur1.y);
        float z6 = fmaf(h, s1.z, cur1.z);
        float q0 = __cosf(z0), q1 = __cosf(z1), q2 = __cosf(z2), q3 = __cosf(z3);
        float q4 = __cosf(z4), q5 = __cosf(z5), q6 = __cosf(z6);
        float pr = ((q0 * q1) * (q2 * q3)) * ((q4 * q5) * q6);
        // gate nonlinearity: sigmoid(x)=1/(1+e^-x); tanh(x)=1-2/(e^{2x}+1)
        float E  = __expf(a * pr);
        float rc = __builtin_amdgcn_rcpf(1.f + E);
        float val = isU ? fmaf(-2.f, rc, 1.f) : rc;
        float f_ = quad_bcast<0>(val);
        float i_ = quad_bcast<1>(val);
        float u_ = quad_bcast<2>(val);
        float o_ = quad_bcast<3>(val);
        c = fmaf(f_, c, i_ * u_);
        float E2 = __expf(2.f * c);
        float th = fmaf(-2.f, __builtin_amdgcn_rcpf(1.f + E2), 1.f);
        h = o_ * th;
        if (lead) *hp = h;
        hp += BB;
        cur0 = n0; cur1 = n1;
    }
    if (lead) c_buf[b] = c;
}

// ---- broadcast h(t,b) into the [T,B,128] output + final (hx,cx) ------------
__global__ __launch_bounds__(256) void qlstm_bcast(
    const float* __restrict__ h_buf, const float* __restrict__ c_buf,
    float4* __restrict__ out4)
{
    const int N1 = TT * BB * 32;       // outs region in float4s
    const int N2 = N1 + BB * 32;       // + final hx
    const int N3 = N2 + BB * 32;       // + final cx
    int stride = gridDim.x * blockDim.x;
    for (int i = blockIdx.x * blockDim.x + threadIdx.x; i < N3; i += stride) {
        float v;
        if (i < N1)      v = h_buf[i >> 5];
        else if (i < N2) v = h_buf[(TT - 1) * BB + ((i - N1) >> 5)];
        else             v = c_buf[(i - N2) >> 5];
        out4[i] = make_float4(v, v, v, v);
    }
}

extern "C" void kernel_launch(void* const* d_in, const int* in_sizes, int n_in,
                              void* d_out, int out_size, void* d_ws, size_t ws_size,
                              hipStream_t stream)
{
    const float* X  = (const float*)d_in[0];
    const float* Wf = (const float*)d_in[1];
    const float* bf = (const float*)d_in[2];
    const float* Wi = (const float*)d_in[3];
    const float* bi = (const float*)d_in[4];
    const float* Wu = (const float*)d_in[5];
    const float* bu = (const float*)d_in[6];
    const float* Wo = (const float*)d_in[7];
    const float* bo = (const float*)d_in[8];
    // d_in[9..12] = qwf/qwi/qwu/qwo: analytically unused.

    float* ws    = (float*)d_ws;
    float* zxb   = ws;                                  // 16.78 MB
    float* h_buf = ws + (size_t)TT * BB * 32;           // 0.52 MB
    float* c_buf = h_buf + (size_t)TT * BB;             // 1 KB
    float* swh   = c_buf + BB;                          // 128 B

    qlstm_prep<<<1, 256, 0, stream>>>(Wf, Wi, Wu, Wo, swh);
    qlstm_zx<<<TT * BB / 16, 256, 0, stream>>>(X, Wf, bf, Wi, bi, Wu, bu, Wo, bo, zxb);
    qlstm_seq<<<BB / 16, 64, 0, stream>>>(zxb, swh, h_buf, c_buf);
    qlstm_bcast<<<4096, 256, 0, stream>>>(h_buf, c_buf, (float4*)d_out);
}

// Round 2
// 190.957 us; speedup vs baseline: 1.3185x; 1.3185x over previous
//
#include <hip/hip_runtime.h>

#define TT 512
#define BB 256
#define DIN 128
#define DH 128
#define PFD 8   // prefetch depth (steps) in the sequential kernel

// ---------------------------------------------------------------------------
// Math simplification (exact, from the reference):
//   cx[b,:] and hx[b,:] are constant across the hidden dim (gates are [B,1]
//   scalars broadcast over D_H and cx starts at 0). So per (t,b) the state is
//   two scalars (h, c):
//     z_j  = zx[t,b,j] + h * swh_j + b_j           (j = 28 gate/qubit combos)
//     p_g  = prod_{q=1..7} cos(z_{g,q})
//     f,i,o = sigmoid(p); u = tanh(p)
//     c = f*c + i*u ;  h = o*tanh(c)
//   outs[t,b,:] = h (broadcast over 128), final hx = h, final cx = c.
//   qwf/qwi/qwu/qwo are analytically dead (diagonal RZ drops out of <Z0>).
// ---------------------------------------------------------------------------

// ws layout (floats):
//   zxb  [TT*BB*32]  : x-projection + bias, slot j' = gate*8 + (q-1); slot 7 = 0
//   h_buf[TT*BB]     : h(t,b)   (also absorbs seq's harmless prefetch overread)
//   c_buf[BB]        : final c(b)
//   swh  [32]        : row-sums of the hx-half of W rows (slot layout as zxb)

// ---- zx: zxb[row][slot] = x(row) . Wx_row + bias; block 0 also fills swh ---
__global__ __launch_bounds__(256) void qlstm_zx(
    const float* __restrict__ X,   // [TT*BB][128]
    const float* __restrict__ Wf, const float* __restrict__ bf,
    const float* __restrict__ Wi, const float* __restrict__ bi,
    const float* __restrict__ Wu, const float* __restrict__ bu,
    const float* __restrict__ Wo, const float* __restrict__ bo,
    float* __restrict__ zxb,       // [TT*BB][32]
    float* __restrict__ swh)       // [32]
{
    __shared__ float Wl[28][132];  // pad 132: float4 rows stay 16B aligned
    int tid = threadIdx.x;
    for (int idx = tid; idx < 28 * 128; idx += 256) {
        int jj = idx >> 7;         // 0..27
        int d  = idx & 127;
        int g  = jj / 7;
        int qi = jj - g * 7;
        const float* W = (g == 0) ? Wf : ((g == 1) ? Wi : ((g == 2) ? Wu : Wo));
        Wl[jj][d] = W[(qi + 1) * 256 + d];
    }
    __syncthreads();

    int rr = tid >> 5;             // 0..7 -> rows rr and rr+8 of this block
    int j  = tid & 31;             // 0..31 (28 compute, 4 write the zero slot)
    long rowbase = (long)blockIdx.x * 16;
    const float4* x0 = (const float4*)(X + (rowbase + rr) * 128);
    const float4* x1 = (const float4*)(X + (rowbase + rr + 8) * 128);
    if (j < 28) {
        int g  = j / 7;
        int qi = j - g * 7;
        const float* bp = (g == 0) ? bf : ((g == 1) ? bi : ((g == 2) ? bu : bo));
        float bias = bp[qi + 1];
        const float4* w4 = (const float4*)(&Wl[j][0]);
        float a0 = 0.f, a1 = 0.f;
#pragma unroll 8
        for (int k = 0; k < 32; ++k) {
            float4 w  = w4[k];
            float4 p0 = x0[k];
            float4 p1 = x1[k];
            a0 = fmaf(w.x, p0.x, a0); a0 = fmaf(w.y, p0.y, a0);
            a0 = fmaf(w.z, p0.z, a0); a0 = fmaf(w.w, p0.w, a0);
            a1 = fmaf(w.x, p1.x, a1); a1 = fmaf(w.y, p1.y, a1);
            a1 = fmaf(w.z, p1.z, a1); a1 = fmaf(w.w, p1.w, a1);
        }
        int slot = g * 8 + qi;
        zxb[(rowbase + rr) * 32 + slot]     = a0 + bias;
        zxb[(rowbase + rr + 8) * 32 + slot] = a1 + bias;
    } else {
        int g = j - 28;
        zxb[(rowbase + rr) * 32 + g * 8 + 7]     = 0.f;
        zxb[(rowbase + rr + 8) * 32 + g * 8 + 7] = 0.f;
    }

    // block 0 additionally computes swh (row-sums of the hx-half of W rows)
    if (blockIdx.x == 0) {
        int slot = tid >> 3;       // 0..31
        int s    = tid & 7;
        int g    = slot >> 3;
        int qi   = slot & 7;
        const float* W = (g == 0) ? Wf : ((g == 1) ? Wi : ((g == 2) ? Wu : Wo));
        float p = 0.f;
        if (qi < 7) {
            const float* row = W + (qi + 1) * 256 + 128 + s * 16;
#pragma unroll
            for (int k = 0; k < 16; ++k) p += row[k];
        }
        p += __shfl_xor(p, 1);
        p += __shfl_xor(p, 2);
        p += __shfl_xor(p, 4);
        if (s == 0) swh[slot] = p;   // qi==7 -> 0 (neutral)
    }
}

// ---- sequential core: 4 lanes per batch chain, DPP quad broadcasts ---------
template <int K>
__device__ __forceinline__ float quad_bcast(float v) {
    // quad_perm broadcast of quad-lane K: ctrl = K|K<<2|K<<4|K<<6 = K*0x55
    return __int_as_float(__builtin_amdgcn_mov_dpp(
        __float_as_int(v), K * 0x55, 0xf, 0xf, true));
}

__global__ __launch_bounds__(64) void qlstm_seq(
    const float* __restrict__ zxb,  // [TT*BB][32]
    const float* __restrict__ swh,  // [32]
    float* __restrict__ h_buf,      // [TT][BB]
    float* __restrict__ c_buf)      // [BB]
{
    int lane = threadIdx.x;                    // 64 = one wave
    int b    = blockIdx.x * 16 + (lane >> 2);  // batch chain
    int g    = lane & 3;                       // 0=f 1=i 2=u 3=o
    float4 s0 = *(const float4*)(swh + g * 8);
    float4 s1 = *(const float4*)(swh + g * 8 + 4);   // s1.w unused (slot 7)
    const float a    = (g == 2) ? 2.f : -1.f;   // exp arg scale: tanh vs sigmoid
    const bool  lead = (g == 0);
    const bool  isU  = (g == 2);

    // 8-deep register prefetch pipeline (static indices after full unroll).
    // Overreads up to 2*PFD-1 steps past zxb's end -> lands inside h_buf
    // ((520-512)*BB*32*4 = 256 KB < 512 KB), values discarded. Safe.
    const float* pl = zxb + b * 32 + g * 8;
    float4 b0[PFD], b1[PFD];
#pragma unroll
    for (int d = 0; d < PFD; ++d) {
        b0[d] = *(const float4*)pl;
        b1[d] = *(const float4*)(pl + 4);
        pl += BB * 32;
    }

    float h = 0.f, c = 0.f;
    float* hp = h_buf + b;
    for (int tb = 0; tb < TT; tb += PFD) {
#pragma unroll
        for (int d = 0; d < PFD; ++d) {
            float4 cur0 = b0[d];
            float4 cur1 = b1[d];
            b0[d] = *(const float4*)pl;          // prefetch step tb+d+PFD
            b1[d] = *(const float4*)(pl + 4);
            pl += BB * 32;
            float z0 = fmaf(h, s0.x, cur0.x);
            float z1 = fmaf(h, s0.y, cur0.y);
            float z2 = fmaf(h, s0.z, cur0.z);
            float z3 = fmaf(h, s0.w, cur0.w);
            float z4 = fmaf(h, s1.x, cur1.x);
            float z5 = fmaf(h, s1.y, cur1.y);
            float z6 = fmaf(h, s1.z, cur1.z);
            float q0 = __cosf(z0), q1 = __cosf(z1), q2 = __cosf(z2), q3 = __cosf(z3);
            float q4 = __cosf(z4), q5 = __cosf(z5), q6 = __cosf(z6);
            float pr = ((q0 * q1) * (q2 * q3)) * ((q4 * q5) * q6);
            // gate nonlinearity: sigmoid(x)=1/(1+e^-x); tanh(x)=1-2/(e^{2x}+1)
            float E  = __expf(a * pr);
            float rc = __builtin_amdgcn_rcpf(1.f + E);
            float val = isU ? fmaf(-2.f, rc, 1.f) : rc;
            float f_ = quad_bcast<0>(val);
            float i_ = quad_bcast<1>(val);
            float u_ = quad_bcast<2>(val);
            float o_ = quad_bcast<3>(val);
            c = fmaf(f_, c, i_ * u_);
            float E2 = __expf(2.f * c);
            float th = fmaf(-2.f, __builtin_amdgcn_rcpf(1.f + E2), 1.f);
            h = o_ * th;
            if (lead) *hp = h;
            hp += BB;
        }
    }
    if (lead) c_buf[b] = c;
}

// ---- broadcast h(t,b) into the [T,B,128] output + final (hx,cx) ------------
__global__ __launch_bounds__(256) void qlstm_bcast(
    const float* __restrict__ h_buf, const float* __restrict__ c_buf,
    float4* __restrict__ out4)
{
    const int N1 = TT * BB * 32;       // outs region in float4s
    const int N2 = N1 + BB * 32;       // + final hx
    const int N3 = N2 + BB * 32;       // + final cx
    int stride = gridDim.x * blockDim.x;
    for (int i = blockIdx.x * blockDim.x + threadIdx.x; i < N3; i += stride) {
        float v;
        if (i < N1)      v = h_buf[i >> 5];
        else if (i < N2) v = h_buf[(TT - 1) * BB + ((i - N1) >> 5)];
        else             v = c_buf[(i - N2) >> 5];
        out4[i] = make_float4(v, v, v, v);
    }
}

extern "C" void kernel_launch(void* const* d_in, const int* in_sizes, int n_in,
                              void* d_out, int out_size, void* d_ws, size_t ws_size,
                              hipStream_t stream)
{
    const float* X  = (const float*)d_in[0];
    const float* Wf = (const float*)d_in[1];
    const float* bf = (const float*)d_in[2];
    const float* Wi = (const float*)d_in[3];
    const float* bi = (const float*)d_in[4];
    const float* Wu = (const float*)d_in[5];
    const float* bu = (const float*)d_in[6];
    const float* Wo = (const float*)d_in[7];
    const float* bo = (const float*)d_in[8];
    // d_in[9..12] = qwf/qwi/qwu/qwo: analytically unused.

    float* ws    = (float*)d_ws;
    float* zxb   = ws;                                  // 16.78 MB
    float* h_buf = ws + (size_t)TT * BB * 32;           // 0.52 MB
    float* c_buf = h_buf + (size_t)TT * BB;             // 1 KB
    float* swh   = c_buf + BB;                          // 128 B

    qlstm_zx<<<TT * BB / 16, 256, 0, stream>>>(X, Wf, bf, Wi, bi, Wu, bu, Wo, bo,
                                               zxb, swh);
    qlstm_seq<<<BB / 16, 64, 0, stream>>>(zxb, swh, h_buf, c_buf);
    qlstm_bcast<<<4096, 256, 0, stream>>>(h_buf, c_buf, (float4*)d_out);
}

// Round 3
// 122.947 us; speedup vs baseline: 2.0478x; 1.5532x over previous
//
#include <hip/hip_runtime.h>

#define TT 512
#define BB 256
#define DIN 128
#define DH 128
#define PFD 8   // prefetch depth (steps) in the sequential kernel

typedef __attribute__((ext_vector_type(8))) short bf16x8;  // 8 bf16 in 4 VGPRs
typedef __attribute__((ext_vector_type(4))) float f32x4;

// ---------------------------------------------------------------------------
// Math simplification (exact, from the reference):
//   gates are [B,1] scalars broadcast over D_H and cx starts at 0, so the
//   whole state per (t,b) is two scalars (h, c):
//     z_j  = zx[t,b,j] + h * swh_j            (j = 28 gate/qubit slots)
//     p_g  = prod_{q=1..7} cos(z_{g,q})
//     f,i,o = sigmoid(p); u = tanh(p)
//     c = f*c + i*u ;  h = o*tanh(c)
//   outs[t,b,:] = h broadcast over 128; qw* are analytically dead.
// zx is a skinny GEMM [131072 x 128] @ [128 x 32] -> MFMA bf16 with hi/lo
// split (3 MFMA terms) for fp32-grade accuracy.
// ---------------------------------------------------------------------------

// ws layout (floats):
//   zxb  [TT*BB*32]  : x-projection + bias, slot = gate*8 + (q-1); slot 7 = 0
//   h_buf[TT*BB]     : h(t,b)  (also absorbs seq's harmless prefetch overread)
//   c_buf[BB]        : final c(b)
//   swh  [32]        : row-sums of the hx-half of W rows
//   bias32[32]       : bias per slot (0 in slots 7/15/23/31)
//   wbh/wbl          : B-fragment-packed bf16 hi/lo of W x-half, 4096 ushort each

__device__ __forceinline__ unsigned short f2bf(float x) {
    unsigned u = __float_as_uint(x);
    return (unsigned short)((u + 0x7fffu + ((u >> 16) & 1u)) >> 16);  // RNE
}

// ---- prep: pack W into B-fragments + bias32 + swh --------------------------
// B-frag element (nt,s,lane,j): n = nt*16 + (lane&15), k = s*32 + (lane>>4)*8 + j
// value = (n&7)<7 ? W_g[((n&7)+1)*256 + k] : 0, g = n>>3.
__global__ __launch_bounds__(256) void qlstm_prep(
    const float* __restrict__ Wf, const float* __restrict__ bf,
    const float* __restrict__ Wi, const float* __restrict__ bi,
    const float* __restrict__ Wu, const float* __restrict__ bu,
    const float* __restrict__ Wo, const float* __restrict__ bo,
    float* __restrict__ swh, float* __restrict__ bias32,
    unsigned short* __restrict__ wbh, unsigned short* __restrict__ wbl)
{
    int tid = threadIdx.x;
    // W fragments
    for (int e = tid; e < 4096; e += 256) {
        int j    = e & 7;
        int lane = (e >> 3) & 63;
        int s    = (e >> 9) & 3;
        int nt   = e >> 11;
        int n    = nt * 16 + (lane & 15);
        int k    = s * 32 + (lane >> 4) * 8 + j;
        int g    = n >> 3;
        int qi   = n & 7;
        const float* W = (g == 0) ? Wf : ((g == 1) ? Wi : ((g == 2) ? Wu : Wo));
        float val = (qi < 7) ? W[(qi + 1) * 256 + k] : 0.f;
        unsigned short h = f2bf(val);
        wbh[e] = h;
        float hf = __uint_as_float(((unsigned)h) << 16);
        wbl[e] = f2bf(val - hf);
    }
    // bias table
    if (tid < 32) {
        int g = tid >> 3, qi = tid & 7;
        const float* bp = (g == 0) ? bf : ((g == 1) ? bi : ((g == 2) ? bu : bo));
        bias32[tid] = (qi < 7) ? bp[qi + 1] : 0.f;
    }
    // swh row-sums (hx-half)
    {
        int slot = tid >> 3, sfx = tid & 7;
        int g = slot >> 3, qi = slot & 7;
        const float* W = (g == 0) ? Wf : ((g == 1) ? Wi : ((g == 2) ? Wu : Wo));
        float p = 0.f;
        if (qi < 7) {
            const float* row = W + (qi + 1) * 256 + 128 + sfx * 16;
#pragma unroll
            for (int k = 0; k < 16; ++k) p += row[k];
        }
        p += __shfl_xor(p, 1);
        p += __shfl_xor(p, 2);
        p += __shfl_xor(p, 4);
        if (sfx == 0) swh[slot] = p;   // qi==7 -> 0 (neutral)
    }
}

// ---- zx: MFMA GEMM  zxb[row][slot] = X[row] . W_slot + bias ----------------
// 4 waves/block, each wave: 16 rows x 32 slots. hi/lo split: 24 MFMA/wave.
__global__ __launch_bounds__(256) void qlstm_zx(
    const float* __restrict__ X,            // [TT*BB][128]
    const unsigned short* __restrict__ wbh, // B-frags hi
    const unsigned short* __restrict__ wbl, // B-frags lo
    const float* __restrict__ bias32,
    float* __restrict__ zxb)                // [TT*BB][32]
{
    int tid  = threadIdx.x;
    int w    = tid >> 6;
    int lane = tid & 63;
    int r    = lane & 15;
    int hi   = lane >> 4;
    long rowbase = (long)blockIdx.x * 64 + w * 16;

    float b0 = bias32[r], b1 = bias32[16 + r];
    f32x4 acc0 = {b0, b0, b0, b0};
    f32x4 acc1 = {b1, b1, b1, b1};

    const float* xrow = X + (rowbase + r) * 128 + hi * 8;
#pragma unroll
    for (int s = 0; s < 4; ++s) {
        float4 xa = *(const float4*)(xrow + s * 32);
        float4 xb = *(const float4*)(xrow + s * 32 + 4);
        float xs[8] = {xa.x, xa.y, xa.z, xa.w, xb.x, xb.y, xb.z, xb.w};
        bf16x8 ah, al;
#pragma unroll
        for (int j = 0; j < 8; ++j) {
            unsigned short hh = f2bf(xs[j]);
            ah[j] = (short)hh;
            float hf = __uint_as_float(((unsigned)hh) << 16);
            al[j] = (short)f2bf(xs[j] - hf);
        }
        bf16x8 bh0 = *(const bf16x8*)(wbh + ((size_t)(0 * 4 + s) * 64 + lane) * 8);
        bf16x8 bl0 = *(const bf16x8*)(wbl + ((size_t)(0 * 4 + s) * 64 + lane) * 8);
        bf16x8 bh1 = *(const bf16x8*)(wbh + ((size_t)(1 * 4 + s) * 64 + lane) * 8);
        bf16x8 bl1 = *(const bf16x8*)(wbl + ((size_t)(1 * 4 + s) * 64 + lane) * 8);
        acc0 = __builtin_amdgcn_mfma_f32_16x16x32_bf16(ah, bh0, acc0, 0, 0, 0);
        acc0 = __builtin_amdgcn_mfma_f32_16x16x32_bf16(al, bh0, acc0, 0, 0, 0);
        acc0 = __builtin_amdgcn_mfma_f32_16x16x32_bf16(ah, bl0, acc0, 0, 0, 0);
        acc1 = __builtin_amdgcn_mfma_f32_16x16x32_bf16(ah, bh1, acc1, 0, 0, 0);
        acc1 = __builtin_amdgcn_mfma_f32_16x16x32_bf16(al, bh1, acc1, 0, 0, 0);
        acc1 = __builtin_amdgcn_mfma_f32_16x16x32_bf16(ah, bl1, acc1, 0, 0, 0);
    }
    // C/D layout (m89-verified): col = lane&15, row = (lane>>4)*4 + reg
    float* zr = zxb + rowbase * 32;
#pragma unroll
    for (int reg = 0; reg < 4; ++reg) {
        int row = hi * 4 + reg;
        zr[row * 32 + r]      = acc0[reg];
        zr[row * 32 + 16 + r] = acc1[reg];
    }
}

// ---- sequential core: 4 lanes per batch chain, DPP quad broadcasts ---------
template <int K>
__device__ __forceinline__ float quad_bcast(float v) {
    return __int_as_float(__builtin_amdgcn_mov_dpp(
        __float_as_int(v), K * 0x55, 0xf, 0xf, true));
}

__global__ __launch_bounds__(64) void qlstm_seq(
    const float* __restrict__ zxb,  // [TT*BB][32]
    const float* __restrict__ swh,  // [32]
    float* __restrict__ h_buf,      // [TT][BB]
    float* __restrict__ c_buf)      // [BB]
{
    int lane = threadIdx.x;                    // 64 = one wave
    int b    = blockIdx.x * 16 + (lane >> 2);  // batch chain
    int g    = lane & 3;                       // 0=f 1=i 2=u 3=o
    float4 s0 = *(const float4*)(swh + g * 8);
    float4 s1 = *(const float4*)(swh + g * 8 + 4);   // s1.w unused (slot 7)
    const float a    = (g == 2) ? 2.f : -1.f;   // exp arg scale: tanh vs sigmoid
    const bool  lead = (g == 0);
    const bool  isU  = (g == 2);

    // 8-deep register prefetch pipeline (static indices after full unroll).
    // Overreads up to 2*PFD-1 steps past zxb's end -> lands inside h_buf
    // ((520-512)*BB*32*4 = 256 KB < 512 KB), values discarded. Safe.
    const float* pl = zxb + b * 32 + g * 8;
    float4 b0[PFD], b1[PFD];
#pragma unroll
    for (int d = 0; d < PFD; ++d) {
        b0[d] = *(const float4*)pl;
        b1[d] = *(const float4*)(pl + 4);
        pl += BB * 32;
    }

    float h = 0.f, c = 0.f;
    float* hp = h_buf + b;
    for (int tb = 0; tb < TT; tb += PFD) {
#pragma unroll
        for (int d = 0; d < PFD; ++d) {
            float4 cur0 = b0[d];
            float4 cur1 = b1[d];
            b0[d] = *(const float4*)pl;          // prefetch step tb+d+PFD
            b1[d] = *(const float4*)(pl + 4);
            pl += BB * 32;
            float z0 = fmaf(h, s0.x, cur0.x);
            float z1 = fmaf(h, s0.y, cur0.y);
            float z2 = fmaf(h, s0.z, cur0.z);
            float z3 = fmaf(h, s0.w, cur0.w);
            float z4 = fmaf(h, s1.x, cur1.x);
            float z5 = fmaf(h, s1.y, cur1.y);
            float z6 = fmaf(h, s1.z, cur1.z);
            float q0 = __cosf(z0), q1 = __cosf(z1), q2 = __cosf(z2), q3 = __cosf(z3);
            float q4 = __cosf(z4), q5 = __cosf(z5), q6 = __cosf(z6);
            float pr = ((q0 * q1) * (q2 * q3)) * ((q4 * q5) * q6);
            // sigmoid(x)=1/(1+e^-x); tanh(x)=1-2/(e^{2x}+1)
            float E  = __expf(a * pr);
            float rc = __builtin_amdgcn_rcpf(1.f + E);
            float val = isU ? fmaf(-2.f, rc, 1.f) : rc;
            float f_ = quad_bcast<0>(val);
            float i_ = quad_bcast<1>(val);
            float u_ = quad_bcast<2>(val);
            float o_ = quad_bcast<3>(val);
            c = fmaf(f_, c, i_ * u_);
            float E2 = __expf(2.f * c);
            float th = fmaf(-2.f, __builtin_amdgcn_rcpf(1.f + E2), 1.f);
            h = o_ * th;
            if (lead) *hp = h;
            hp += BB;
        }
    }
    if (lead) c_buf[b] = c;
}

// ---- broadcast h(t,b) into the [T,B,128] output + final (hx,cx) ------------
__global__ __launch_bounds__(256) void qlstm_bcast(
    const float* __restrict__ h_buf, const float* __restrict__ c_buf,
    float4* __restrict__ out4)
{
    const int N1 = TT * BB * 32;       // outs region in float4s
    const int N2 = N1 + BB * 32;       // + final hx
    const int N3 = N2 + BB * 32;       // + final cx
    int stride = gridDim.x * blockDim.x;
    for (int i = blockIdx.x * blockDim.x + threadIdx.x; i < N3; i += stride) {
        float v;
        if (i < N1)      v = h_buf[i >> 5];
        else if (i < N2) v = h_buf[(TT - 1) * BB + ((i - N1) >> 5)];
        else             v = c_buf[(i - N2) >> 5];
        out4[i] = make_float4(v, v, v, v);
    }
}

extern "C" void kernel_launch(void* const* d_in, const int* in_sizes, int n_in,
                              void* d_out, int out_size, void* d_ws, size_t ws_size,
                              hipStream_t stream)
{
    const float* X  = (const float*)d_in[0];
    const float* Wf = (const float*)d_in[1];
    const float* bf = (const float*)d_in[2];
    const float* Wi = (const float*)d_in[3];
    const float* bi = (const float*)d_in[4];
    const float* Wu = (const float*)d_in[5];
    const float* bu = (const float*)d_in[6];
    const float* Wo = (const float*)d_in[7];
    const float* bo = (const float*)d_in[8];
    // d_in[9..12] = qwf/qwi/qwu/qwo: analytically unused.

    float* ws    = (float*)d_ws;
    float* zxb   = ws;                                  // 16.78 MB
    float* h_buf = ws + (size_t)TT * BB * 32;           // 0.52 MB
    float* c_buf = h_buf + (size_t)TT * BB;             // 1 KB
    float* swh   = c_buf + BB;                          // 128 B
    float* bias32 = swh + 32;                           // 128 B
    unsigned short* wbh = (unsigned short*)(bias32 + 32);  // 8 KB
    unsigned short* wbl = wbh + 4096;                      // 8 KB

    qlstm_prep<<<1, 256, 0, stream>>>(Wf, bf, Wi, bi, Wu, bu, Wo, bo,
                                      swh, bias32, wbh, wbl);
    qlstm_zx<<<TT * BB / 64, 256, 0, stream>>>(X, wbh, wbl, bias32, zxb);
    qlstm_seq<<<BB / 16, 64, 0, stream>>>(zxb, swh, h_buf, c_buf);
    qlstm_bcast<<<4096, 256, 0, stream>>>(h_buf, c_buf, (float4*)d_out);
}